// Round 1
// baseline (888.721 us; speedup 1.0000x reference)
//
#include <hip/hip_runtime.h>

typedef short short8 __attribute__((ext_vector_type(8)));
typedef float f32x4 __attribute__((ext_vector_type(4)));

#define DEVI __device__ __forceinline__

constexpr int BATCH = 8;
constexpr int NPTS  = 65536;     // points per batch
constexpr int CIN   = 6;
constexpr int H0    = 128;
constexpr int H1    = 256;
constexpr int NCTR  = 1024;
constexpr int MB    = 64;        // points per block

// a-tile strides (shorts), padded for bank-conflict-free ds_read_b128
constexpr int A1S = 136;         // 128 + 8
constexpr int A2S = 264;         // 256 + 8

// workspace layout
constexpr size_t Y_BYTES = (size_t)BATCH * NCTR * H0 * 4;      // 4 MiB fp32
constexpr size_t W2T_OFF = Y_BYTES;
constexpr size_t W3T_OFF = W2T_OFF + (size_t)H0 * H0 * 2;
constexpr size_t W4T_OFF = W3T_OFF + (size_t)H1 * H1 * 2;
constexpr size_t WS_NEED = W4T_OFF + (size_t)H1 * H1 * 2;

DEVI unsigned short f2bf(float f) {
    unsigned u = __float_as_uint(f);
    u += 0x7fffu + ((u >> 16) & 1u);          // round-to-nearest-even
    return (unsigned short)(u >> 16);
}
DEVI float gelu(float x) { return 0.5f * x * (1.f + erff(x * 0.70710678118654752f)); }

// ---------------- conv1: gelu(LN(p@w1+b1)) -> a1[64][A1S] bf16 ----------------
DEVI void conv1_tile(int tid, const float* s_pts, const float* s_w1,
                     const float* s_b1, const float* s_g1, const float* s_be1,
                     unsigned short* a1)
{
    const int p = tid >> 2, sub = tid & 3;    // 4 threads per point, c = 4j+sub
    float pt[CIN];
#pragma unroll
    for (int k = 0; k < CIN; ++k) pt[k] = s_pts[p * CIN + k];
    float h[32];
#pragma unroll
    for (int j = 0; j < 32; ++j) {
        const int c = (j << 2) + sub;
        float a = s_b1[c];
#pragma unroll
        for (int k = 0; k < CIN; ++k) a = fmaf(pt[k], s_w1[k * H0 + c], a);
        h[j] = a;
    }
    float s = 0.f, s2 = 0.f;
#pragma unroll
    for (int j = 0; j < 32; ++j) { s += h[j]; s2 = fmaf(h[j], h[j], s2); }
    s  += __shfl_xor(s, 1);  s  += __shfl_xor(s, 2);
    s2 += __shfl_xor(s2, 1); s2 += __shfl_xor(s2, 2);
    const float mean = s * (1.f / H0);
    const float rstd = rsqrtf(s2 * (1.f / H0) - mean * mean + 1e-5f);
#pragma unroll
    for (int j = 0; j < 32; ++j) {
        const int c = (j << 2) + sub;
        float v = fmaf((h[j] - mean) * rstd, s_g1[c], s_be1[c]);
        a1[p * A1S + c] = f2bf(gelu(v));
    }
}

// ---------------- GEMM2: a1[64][128] @ w2T -> acc[4][2] ----------------
DEVI void gemm2(int lane, int wave, const unsigned short* a1,
                const unsigned short* __restrict__ w2T, f32x4 (&acc)[4][2])
{
    const int q = lane >> 4, colw = lane & 15, n0 = wave * 32;
#pragma unroll
    for (int ks = 0; ks < 4; ++ks) {
        short8 af[4], bfr[2];
#pragma unroll
        for (int mt = 0; mt < 4; ++mt)
            af[mt] = *(const short8*)&a1[(mt * 16 + colw) * A1S + ks * 32 + q * 8];
#pragma unroll
        for (int nt = 0; nt < 2; ++nt)
            bfr[nt] = *(const short8*)&w2T[(n0 + nt * 16 + colw) * H0 + ks * 32 + q * 8];
#pragma unroll
        for (int mt = 0; mt < 4; ++mt)
#pragma unroll
            for (int nt = 0; nt < 2; ++nt)
                acc[mt][nt] = __builtin_amdgcn_mfma_f32_16x16x32_bf16(
                    af[mt], bfr[nt], acc[mt][nt], 0, 0, 0);
    }
}

// ---------------- prep: weight convert/transpose ----------------
__global__ __launch_bounds__(256) void k_prep(
    const float* __restrict__ w2, const float* __restrict__ w3,
    const float* __restrict__ w4,
    unsigned short* __restrict__ w2T, unsigned short* __restrict__ w3T,
    unsigned short* __restrict__ w4T)
{
    int t = blockIdx.x * 256 + threadIdx.x;
    if (t < H0 * H0) {
        int n = t >> 7, k = t & 127;
        w2T[t] = f2bf(w2[k * H0 + n]);
    }
    int t3 = t - H0 * H0;
    if (t3 >= 0 && t3 < H1 * H1) {
        int n = t3 >> 8, k = t3 & 255;
        w3T[t3] = f2bf(w3[k * H1 + n]);
    }
    int t4 = t - (H0 * H0 + H1 * H1);
    if (t4 >= 0 && t4 < H1 * H1) {
        int n = t4 >> 8, k = t4 & 255;
        w4T[t4] = f2bf(w4[k * H1 + n]);
    }
}

// ---------------- phase 1: conv1 MLP + scatter-max into y ----------------
__global__ __launch_bounds__(256) void k_phase1(
    const float* __restrict__ pts, const int* __restrict__ nn_idx,
    const float* __restrict__ w1, const float* __restrict__ b1,
    const float* __restrict__ g1, const float* __restrict__ be1,
    const unsigned short* __restrict__ w2T, const float* __restrict__ b2,
    float* __restrict__ y)
{
    __shared__ __align__(16) float s_pts[MB * CIN];
    __shared__ int   s_idx[MB];
    __shared__ float s_w1[CIN * H0];
    __shared__ float s_b1[H0], s_g1[H0], s_be1[H0], s_b2[H0];
    __shared__ __align__(16) unsigned short a1[MB * A1S];

    const int tid = threadIdx.x;
    const int P0  = blockIdx.x * MB;
    const int b   = P0 >> 16;               // N = 65536

    if (tid < 96) *(float4*)&s_pts[tid * 4] = *(const float4*)&pts[P0 * CIN + tid * 4];
    if (tid < MB) s_idx[tid] = nn_idx[P0 + tid];
    for (int i = tid; i < CIN * H0; i += 256) s_w1[i] = w1[i];
    if (tid < H0) { s_b1[tid] = b1[tid]; s_g1[tid] = g1[tid]; s_be1[tid] = be1[tid]; s_b2[tid] = b2[tid]; }
    __syncthreads();

    conv1_tile(tid, s_pts, s_w1, s_b1, s_g1, s_be1, a1);
    __syncthreads();

    f32x4 acc[4][2] = {};
    const int lane = tid & 63, wave = tid >> 6;
    gemm2(lane, wave, a1, w2T, acc);

    const int q = lane >> 4, colw = lane & 15, n0 = wave * 32;
#pragma unroll
    for (int mt = 0; mt < 4; ++mt)
#pragma unroll
        for (int nt = 0; nt < 2; ++nt)
#pragma unroll
            for (int r = 0; r < 4; ++r) {
                const int row = mt * 16 + q * 4 + r;
                const int col = n0 + nt * 16 + colw;
                float v = acc[mt][nt][r] + s_b2[col];
                if (v > 0.f)
                    atomicMax((int*)&y[((b << 10) + s_idx[row]) * H0 + col],
                              __float_as_int(v));
            }
}

// ---------------- phase 2: recompute x, gather y, conv2 MLP + scatter-max ----------------
__global__ __launch_bounds__(256) void k_phase2(
    const float* __restrict__ pts, const int* __restrict__ nn_idx,
    const float* __restrict__ w1, const float* __restrict__ b1,
    const float* __restrict__ g1, const float* __restrict__ be1,
    const unsigned short* __restrict__ w2T, const float* __restrict__ b2,
    const float* __restrict__ y,
    const unsigned short* __restrict__ w3T, const float* __restrict__ b3,
    const float* __restrict__ g2, const float* __restrict__ be2,
    const unsigned short* __restrict__ w4T, const float* __restrict__ b4,
    float* __restrict__ outp)
{
    __shared__ __align__(16) float s_pts[MB * CIN];
    __shared__ int   s_idx[MB];
    __shared__ float s_w1[CIN * H0];
    __shared__ float s_b1[H0], s_g1[H0], s_be1[H0], s_b2[H0];
    __shared__ float s_b3[H1], s_g2[H1], s_be2[H1], s_b4[H1];
    __shared__ __align__(16) unsigned short a1[MB * A1S];
    __shared__ __align__(16) unsigned short a2[MB * A2S];
    __shared__ float2 s_stats[MB * 4];
    __shared__ float2 s_rowstat[MB];

    const int tid = threadIdx.x;
    const int P0  = blockIdx.x * MB;
    const int b   = P0 >> 16;

    if (tid < 96) *(float4*)&s_pts[tid * 4] = *(const float4*)&pts[P0 * CIN + tid * 4];
    if (tid < MB) s_idx[tid] = nn_idx[P0 + tid];
    for (int i = tid; i < CIN * H0; i += 256) s_w1[i] = w1[i];
    if (tid < H0) { s_b1[tid] = b1[tid]; s_g1[tid] = g1[tid]; s_be1[tid] = be1[tid]; s_b2[tid] = b2[tid]; }
    if (tid < H1) { s_b3[tid] = b3[tid]; s_g2[tid] = g2[tid]; s_be2[tid] = be2[tid]; s_b4[tid] = b4[tid]; }
    __syncthreads();

    conv1_tile(tid, s_pts, s_w1, s_b1, s_g1, s_be1, a1);
    __syncthreads();

    f32x4 acc2[4][2] = {};
    const int lane = tid & 63, wave = tid >> 6;
    gemm2(lane, wave, a1, w2T, acc2);

    const int q = lane >> 4, colw = lane & 15;
    {   // x -> a2 cols [128..256)
        const int n0 = wave * 32;
#pragma unroll
        for (int mt = 0; mt < 4; ++mt)
#pragma unroll
            for (int nt = 0; nt < 2; ++nt)
#pragma unroll
                for (int r = 0; r < 4; ++r) {
                    const int row = mt * 16 + q * 4 + r;
                    const int col = n0 + nt * 16 + colw;
                    a2[row * A2S + H0 + col] = f2bf(acc2[mt][nt][r] + s_b2[col]);
                }
    }
    {   // gather y -> a2 cols [0..128)
        const int p = tid >> 2, sub = tid & 3;
        const float* yrow = y + ((size_t)((b << 10) + s_idx[p])) * H0;
#pragma unroll
        for (int j4 = 0; j4 < 8; ++j4) {
            const int c = sub * 32 + j4 * 4;
            float4 v = *(const float4*)&yrow[c];
            uint2 pk;
            pk.x = (unsigned)f2bf(v.x) | ((unsigned)f2bf(v.y) << 16);
            pk.y = (unsigned)f2bf(v.z) | ((unsigned)f2bf(v.w) << 16);
            *(uint2*)&a2[p * A2S + c] = pk;
        }
    }
    __syncthreads();

    // ---- GEMM3: a2[64][256] @ w3T ----
    f32x4 acc3[4][4] = {};
    const int n0 = wave * 64;
#pragma unroll
    for (int ks = 0; ks < 8; ++ks) {
        short8 af[4], bfr[4];
#pragma unroll
        for (int mt = 0; mt < 4; ++mt)
            af[mt] = *(const short8*)&a2[(mt * 16 + colw) * A2S + ks * 32 + q * 8];
#pragma unroll
        for (int nt = 0; nt < 4; ++nt)
            bfr[nt] = *(const short8*)&w3T[(n0 + nt * 16 + colw) * H1 + ks * 32 + q * 8];
#pragma unroll
        for (int mt = 0; mt < 4; ++mt)
#pragma unroll
            for (int nt = 0; nt < 4; ++nt)
                acc3[mt][nt] = __builtin_amdgcn_mfma_f32_16x16x32_bf16(
                    af[mt], bfr[nt], acc3[mt][nt], 0, 0, 0);
    }

    // + b3, then LN stats (sum / sumsq per row of 256)
#pragma unroll
    for (int mt = 0; mt < 4; ++mt)
#pragma unroll
        for (int nt = 0; nt < 4; ++nt)
#pragma unroll
            for (int r = 0; r < 4; ++r)
                acc3[mt][nt][r] += s_b3[n0 + nt * 16 + colw];

#pragma unroll
    for (int mt = 0; mt < 4; ++mt)
#pragma unroll
        for (int r = 0; r < 4; ++r) {
            float s = 0.f, s2 = 0.f;
#pragma unroll
            for (int nt = 0; nt < 4; ++nt) {
                float v = acc3[mt][nt][r];
                s += v; s2 = fmaf(v, v, s2);
            }
            s  += __shfl_xor(s, 1);  s  += __shfl_xor(s, 2);
            s  += __shfl_xor(s, 4);  s  += __shfl_xor(s, 8);
            s2 += __shfl_xor(s2, 1); s2 += __shfl_xor(s2, 2);
            s2 += __shfl_xor(s2, 4); s2 += __shfl_xor(s2, 8);
            if (colw == 0)
                s_stats[(mt * 16 + q * 4 + r) * 4 + wave] = make_float2(s, s2);
        }
    __syncthreads();
    if (tid < MB) {
        float S = 0.f, S2 = 0.f;
#pragma unroll
        for (int w = 0; w < 4; ++w) { float2 t = s_stats[tid * 4 + w]; S += t.x; S2 += t.y; }
        const float mean = S * (1.f / H1);
        const float rstd = rsqrtf(S2 * (1.f / H1) - mean * mean + 1e-5f);
        s_rowstat[tid] = make_float2(mean, rstd);
    }
    __syncthreads();

    // normalize + gelu -> h back into a2 (full 256 cols)
#pragma unroll
    for (int mt = 0; mt < 4; ++mt)
#pragma unroll
        for (int r = 0; r < 4; ++r) {
            const int row = mt * 16 + q * 4 + r;
            const float2 ms = s_rowstat[row];
#pragma unroll
            for (int nt = 0; nt < 4; ++nt) {
                const int col = n0 + nt * 16 + colw;
                float v = (acc3[mt][nt][r] - ms.x) * ms.y;
                v = fmaf(v, s_g2[col], s_be2[col]);
                a2[row * A2S + col] = f2bf(gelu(v));
            }
        }
    __syncthreads();

    // ---- GEMM4: h[64][256] @ w4T ----
    f32x4 acc4[4][4] = {};
#pragma unroll
    for (int ks = 0; ks < 8; ++ks) {
        short8 af[4], bfr[4];
#pragma unroll
        for (int mt = 0; mt < 4; ++mt)
            af[mt] = *(const short8*)&a2[(mt * 16 + colw) * A2S + ks * 32 + q * 8];
#pragma unroll
        for (int nt = 0; nt < 4; ++nt)
            bfr[nt] = *(const short8*)&w4T[(n0 + nt * 16 + colw) * H1 + ks * 32 + q * 8];
#pragma unroll
        for (int mt = 0; mt < 4; ++mt)
#pragma unroll
            for (int nt = 0; nt < 4; ++nt)
                acc4[mt][nt] = __builtin_amdgcn_mfma_f32_16x16x32_bf16(
                    af[mt], bfr[nt], acc4[mt][nt], 0, 0, 0);
    }

    // epilogue: + b4, scatter-max into out
#pragma unroll
    for (int mt = 0; mt < 4; ++mt)
#pragma unroll
        for (int nt = 0; nt < 4; ++nt)
#pragma unroll
            for (int r = 0; r < 4; ++r) {
                const int row = mt * 16 + q * 4 + r;
                const int col = n0 + nt * 16 + colw;
                float v = acc4[mt][nt][r] + s_b4[col];
                if (v > 0.f)
                    atomicMax((int*)&outp[((size_t)((b << 10) + s_idx[row])) * H1 + col],
                              __float_as_int(v));
            }
}

extern "C" void kernel_launch(void* const* d_in, const int* in_sizes, int n_in,
                              void* d_out, int out_size, void* d_ws, size_t ws_size,
                              hipStream_t stream)
{
    const float* pts = (const float*)d_in[0];
    const int*   nn  = (const int*)d_in[1];
    // d_in[2] = center_number (1024), fixed
    const float* w1  = (const float*)d_in[3];
    const float* b1  = (const float*)d_in[4];
    const float* g1  = (const float*)d_in[5];
    const float* be1 = (const float*)d_in[6];
    const float* w2  = (const float*)d_in[7];
    const float* b2  = (const float*)d_in[8];
    const float* w3  = (const float*)d_in[9];
    const float* b3  = (const float*)d_in[10];
    const float* g2  = (const float*)d_in[11];
    const float* be2 = (const float*)d_in[12];
    const float* w4  = (const float*)d_in[13];
    const float* b4  = (const float*)d_in[14];

    if (ws_size < WS_NEED) return;   // would corrupt memory otherwise; fail loudly

    char* ws = (char*)d_ws;
    float*          y   = (float*)(ws);
    unsigned short* w2T = (unsigned short*)(ws + W2T_OFF);
    unsigned short* w3T = (unsigned short*)(ws + W3T_OFF);
    unsigned short* w4T = (unsigned short*)(ws + W4T_OFF);
    float* outp = (float*)d_out;

    hipMemsetAsync(y, 0, Y_BYTES, stream);
    hipMemsetAsync(outp, 0, (size_t)out_size * sizeof(float), stream);

    k_prep<<<576, 256, 0, stream>>>(w2, w3, w4, w2T, w3T, w4T);

    const int nblk = BATCH * NPTS / MB;   // 8192
    k_phase1<<<nblk, 256, 0, stream>>>(pts, nn, w1, b1, g1, be1, w2T, b2, y);
    k_phase2<<<nblk, 256, 0, stream>>>(pts, nn, w1, b1, g1, be1, w2T, b2, y,
                                       w3T, b3, g2, be2, w4T, b4, outp);
}